// Round 6
// baseline (536.030 us; speedup 1.0000x reference)
//
#include <hip/hip_runtime.h>
#include <hip/hip_bf16.h>
#include <hip/hip_fp8.h>

typedef __hip_bfloat16 bf16;
typedef __attribute__((ext_vector_type(8))) short short8;
typedef __attribute__((ext_vector_type(4))) float floatx4;
typedef __attribute__((ext_vector_type(4))) short shortx4;

static constexpr int BATCH = 4;
static constexpr int CH    = 512;   // C
static constexpr int SEQ   = 4096;  // H*W
static constexpr int DM    = 512;   // model dim

// fp8 scales
static constexpr float SQK = 16.0f;      // Q,K pre-scale
static constexpr float SE  = 16.0f;      // E pre-scale
static constexpr float SV  = 32.0f;      // V pre-scale
// logit factor: model-dim softmax scale / (SQK*SQK)
static constexpr float KQ  = 0.04419417382415922f / 256.0f;
// PV normalize: 1/(SE*SV) folded into rowsum inverse
static constexpr float SEV = 512.0f;

__device__ __forceinline__ void gload16(const void* g, void* l) {
  __builtin_amdgcn_global_load_lds(
      (const __attribute__((address_space(1))) unsigned int*)g,
      (__attribute__((address_space(3))) unsigned int*)l,
      16, 0, 0);
}

__device__ __forceinline__ unsigned char to_fp8(float v) {
  return __hip_cvt_float_to_fp8(v, __HIP_SATFINITE, __HIP_E4M3);
}

// ---------------------------------------------------------------------------
// Weight fp32 -> bf16 conversion (3 matrices of 512x512: Wq, Wk, Wo)
// ---------------------------------------------------------------------------
__global__ __launch_bounds__(256) void cvt_weights(
    const float* __restrict__ w0, const float* __restrict__ w1,
    const float* __restrict__ w2, bf16* __restrict__ out) {
  const float* src = (blockIdx.y == 0) ? w0 : (blockIdx.y == 1) ? w1 : w2;
  int idx = blockIdx.x * 256 + threadIdx.x;
  out[(long)blockIdx.y * (DM * CH) + idx] = __float2bfloat16(src[idx]);
}

// ---------------------------------------------------------------------------
// 512x512 fp32 -> bf16 TRANSPOSED: out[c,d] = in[d,c]
// ---------------------------------------------------------------------------
__global__ __launch_bounds__(256) void transpose_cvt_w(
    const float* __restrict__ in, bf16* __restrict__ out) {
  __shared__ float tile[64][65];
  const int c0 = blockIdx.x * 64, d0 = blockIdx.y * 64;
  const int t = threadIdx.x;
  const int cl = t & 63, dq = t >> 6;
  #pragma unroll
  for (int i = 0; i < 16; ++i) {
    int dl = dq * 16 + i;
    tile[dl][cl] = in[(d0 + dl) * 512 + c0 + cl];
  }
  __syncthreads();
  const int dl2 = t & 63, cq = t >> 6;
  #pragma unroll
  for (int i = 0; i < 16; ++i) {
    int cl2 = cq * 16 + i;
    out[(c0 + cl2) * 512 + d0 + dl2] = __float2bfloat16(tile[dl2][cl2]);
  }
}

// ---------------------------------------------------------------------------
// x (b,c,s) fp32 -> xT (b,s,c) bf16, 64x64 LDS tiles
// ---------------------------------------------------------------------------
__global__ __launch_bounds__(256) void transpose_cvt(
    const float* __restrict__ x, bf16* __restrict__ xT) {
  __shared__ float tile[64][65];
  const int s0 = blockIdx.x * 64, c0 = blockIdx.y * 64;
  const float* xb = x + (long)blockIdx.z * CH * SEQ;
  bf16* xTb = xT + (long)blockIdx.z * SEQ * CH;
  const int t = threadIdx.x;
  const int sl = t & 63, cq = t >> 6;
  #pragma unroll
  for (int i = 0; i < 16; ++i) {
    int cl = cq * 16 + i;
    tile[cl][sl] = xb[(long)(c0 + cl) * SEQ + s0 + sl];
  }
  __syncthreads();
  const int cl2 = t & 63, sq = t >> 6;
  #pragma unroll
  for (int i = 0; i < 16; ++i) {
    int sl2 = sq * 16 + i;
    xTb[(long)(s0 + sl2) * CH + c0 + cl2] = __float2bfloat16(tile[cl2][sl2]);
  }
}

// ---------------------------------------------------------------------------
// bias2[c] = bo[c] + sum_d Wo[c,d] * bv[d]
// ---------------------------------------------------------------------------
__global__ __launch_bounds__(256) void bias_combine(
    const float* __restrict__ Wo, const float* __restrict__ bv,
    const float* __restrict__ bo, float* __restrict__ bias2) {
  int c = blockIdx.x * 256 + threadIdx.x;
  float s = 0.f;
  for (int d = 0; d < DM; ++d) s += Wo[c * DM + d] * bv[d];
  bias2[c] = s + bo[c];
}

// ---------------------------------------------------------------------------
// zero fp32 buffer (rowsum init; ws is poisoned 0xAA before every launch)
// ---------------------------------------------------------------------------
__global__ __launch_bounds__(256) void zero_f32(float* __restrict__ p) {
  p[blockIdx.x * 256 + threadIdx.x] = 0.f;
}

// ---------------------------------------------------------------------------
// BT GEMM 128x128 bf16, plain bf16 out (used for Wvo = Wo*Wv, 512^3)
// ---------------------------------------------------------------------------
__global__ __launch_bounds__(256) void gemm_bt_w(
    const bf16* __restrict__ A, const bf16* __restrict__ B,
    bf16* __restrict__ C, int K, int ldc) {
  __shared__ bf16 At[128 * 32];
  __shared__ bf16 Bt[128 * 32];
  const int tid = threadIdx.x;
  const long lK = K;
  const bf16* Ab = A + (long)blockIdx.y * 128 * lK;
  const bf16* Bb = B + (long)blockIdx.x * 128 * lK;

  const int w = tid >> 6, lane = tid & 63;
  const int wm = (w & 1) << 6, wn = (w >> 1) << 6;
  const int l16 = lane & 15, quad = lane >> 4;

  floatx4 acc[4][4];
  #pragma unroll
  for (int i = 0; i < 4; ++i)
    #pragma unroll
    for (int j = 0; j < 4; ++j) acc[i][j] = (floatx4)(0.0f);

  const int row0 = tid >> 2;
  const int col0 = (tid & 3) << 3;
  const int nk = K >> 5;
  for (int kt = 0; kt < nk; ++kt) {
    const bf16* Ak = Ab + (kt << 5);
    const bf16* Bk = Bb + (kt << 5);
    gload16(Ak + (long)row0 * lK + col0,        (char*)At + tid * 16);
    gload16(Ak + (long)(row0 + 64) * lK + col0, (char*)At + (tid + 256) * 16);
    gload16(Bk + (long)row0 * lK + col0,        (char*)Bt + tid * 16);
    gload16(Bk + (long)(row0 + 64) * lK + col0, (char*)Bt + (tid + 256) * 16);
    __syncthreads();
    short8 af[4], bfr[4];
    #pragma unroll
    for (int i = 0; i < 4; ++i)
      af[i] = *(const short8*)(At + (wm + i * 16 + l16) * 32 + (quad << 3));
    #pragma unroll
    for (int j = 0; j < 4; ++j)
      bfr[j] = *(const short8*)(Bt + (wn + j * 16 + l16) * 32 + (quad << 3));
    #pragma unroll
    for (int i = 0; i < 4; ++i)
      #pragma unroll
      for (int j = 0; j < 4; ++j)
        acc[i][j] = __builtin_amdgcn_mfma_f32_16x16x32_bf16(af[i], bfr[j],
                                                            acc[i][j], 0, 0, 0);
    __syncthreads();
  }

  const int mbase = blockIdx.y * 128 + wm + quad * 4;
  const int nbase = blockIdx.x * 128 + wn + l16;
  #pragma unroll
  for (int i = 0; i < 4; ++i) {
    const int row = mbase + i * 16;
    #pragma unroll
    for (int j = 0; j < 4; ++j) {
      const int col = nbase + j * 16;
      #pragma unroll
      for (int r = 0; r < 4; ++r)
        C[(long)(row + r) * ldc + col] = __float2bfloat16(acc[i][j][r]);
    }
  }
}

// ---------------------------------------------------------------------------
// Projection GEMM 128x64, bf16 in, fp8 out.
// MODE 10: Q8/K8[row*DM+col] = fp8(SQK*(v+bias[col]))         (bias non-null)
// MODE 11: V8t[col*SEQ+row]  = fp8(SV*v), 4-byte packed store (no bias)
// ---------------------------------------------------------------------------
template <int MODE>
__global__ __launch_bounds__(256) void gemm_proj_f8(
    const bf16* __restrict__ A, long sAz,
    const bf16* __restrict__ B,
    unsigned char* __restrict__ C8, long sCz,
    const float* __restrict__ bias) {
  __shared__ bf16 At[128 * 32];
  __shared__ bf16 Bt[64 * 32];
  const int tid = threadIdx.x;
  const int z = blockIdx.z;
  const long lK = CH;
  const bf16* Ab = A + (long)z * sAz + (long)blockIdx.y * 128 * lK;
  const bf16* Bb = B + (long)blockIdx.x * 64 * lK;

  const int w = tid >> 6, lane = tid & 63;
  const int wm = (w & 1) << 6, wn = (w >> 1) << 5;
  const int l16 = lane & 15, quad = lane >> 4;

  floatx4 acc[4][2];
  #pragma unroll
  for (int i = 0; i < 4; ++i)
    #pragma unroll
    for (int j = 0; j < 2; ++j) acc[i][j] = (floatx4)(0.0f);

  const int row0 = tid >> 2;
  const int col0 = (tid & 3) << 3;
  for (int kt = 0; kt < CH / 32; ++kt) {
    const bf16* Ak = Ab + (kt << 5);
    const bf16* Bk = Bb + (kt << 5);
    gload16(Ak + (long)row0 * lK + col0,        (char*)At + tid * 16);
    gload16(Ak + (long)(row0 + 64) * lK + col0, (char*)At + (tid + 256) * 16);
    gload16(Bk + (long)row0 * lK + col0,        (char*)Bt + tid * 16);
    __syncthreads();
    short8 af[4], bfr[2];
    #pragma unroll
    for (int i = 0; i < 4; ++i)
      af[i] = *(const short8*)(At + (wm + i * 16 + l16) * 32 + (quad << 3));
    #pragma unroll
    for (int j = 0; j < 2; ++j)
      bfr[j] = *(const short8*)(Bt + (wn + j * 16 + l16) * 32 + (quad << 3));
    #pragma unroll
    for (int i = 0; i < 4; ++i)
      #pragma unroll
      for (int j = 0; j < 2; ++j)
        acc[i][j] = __builtin_amdgcn_mfma_f32_16x16x32_bf16(af[i], bfr[j],
                                                            acc[i][j], 0, 0, 0);
    __syncthreads();
  }

  const int mbase = blockIdx.y * 128 + wm + quad * 4;
  const int nbase = blockIdx.x * 64 + wn + l16;
  unsigned char* C = C8 + (long)z * sCz;
  #pragma unroll
  for (int i = 0; i < 4; ++i) {
    const int row = mbase + i * 16;
    #pragma unroll
    for (int j = 0; j < 2; ++j) {
      const int col = nbase + j * 16;
      floatx4 v = acc[i][j];
      if constexpr (MODE == 10) {
        const float bb = bias[col];
        #pragma unroll
        for (int r = 0; r < 4; ++r)
          C[(long)(row + r) * DM + col] = to_fp8(SQK * (v[r] + bb));
      } else {  // MODE 11: packed transposed
        unsigned int p = (unsigned int)to_fp8(SV * v[0])
                       | ((unsigned int)to_fp8(SV * v[1]) << 8)
                       | ((unsigned int)to_fp8(SV * v[2]) << 16)
                       | ((unsigned int)to_fp8(SV * v[3]) << 24);
        *(unsigned int*)(C + (long)col * SEQ + row) = p;
      }
    }
  }
}

// ---------------------------------------------------------------------------
// QK^T fp8 GEMM 128x128, BK=64, + exp epilogue -> E8 + atomic rowsum.
// A = Q8 (s,d), B = K8 (t,d), both MxK row-major fp8, K=DM.
// ---------------------------------------------------------------------------
__global__ __launch_bounds__(256) void gemm_qkt_exp_f8(
    const unsigned char* __restrict__ Q8, const unsigned char* __restrict__ K8,
    unsigned char* __restrict__ E8, float* __restrict__ rowsum) {
  __shared__ unsigned char At[128 * 64];
  __shared__ unsigned char Bt[128 * 64];
  const int tid = threadIdx.x;
  const int z = blockIdx.z;
  const long lK = DM;
  const unsigned char* Ab = Q8 + (long)z * SEQ * DM + (long)blockIdx.y * 128 * lK;
  const unsigned char* Bb = K8 + (long)z * SEQ * DM + (long)blockIdx.x * 128 * lK;

  const int w = tid >> 6, lane = tid & 63;
  const int wm = (w & 1) << 6, wn = (w >> 1) << 6;
  const int l16 = lane & 15, quad = lane >> 4;

  floatx4 acc[4][4];
  #pragma unroll
  for (int i = 0; i < 4; ++i)
    #pragma unroll
    for (int j = 0; j < 4; ++j) acc[i][j] = (floatx4)(0.0f);

  const int row0 = tid >> 2;          // 0..63 (row pairs: +64 on 2nd stage)
  const int part = (tid & 3) << 4;    // byte offset 0,16,32,48
  for (int kt = 0; kt < DM / 64; ++kt) {
    const unsigned char* Ak = Ab + (kt << 6);
    const unsigned char* Bk = Bb + (kt << 6);
    gload16(Ak + (long)row0 * lK + part,        (char*)At + tid * 16);
    gload16(Ak + (long)(row0 + 64) * lK + part, (char*)At + (tid + 256) * 16);
    gload16(Bk + (long)row0 * lK + part,        (char*)Bt + tid * 16);
    gload16(Bk + (long)(row0 + 64) * lK + part, (char*)Bt + (tid + 256) * 16);
    __syncthreads();
    long af[4][2], bfr[4][2];
    #pragma unroll
    for (int i = 0; i < 4; ++i) {
      const unsigned char* p = At + (wm + i * 16 + l16) * 64 + (quad << 3);
      af[i][0] = *(const long*)p;
      af[i][1] = *(const long*)(p + 32);
    }
    #pragma unroll
    for (int j = 0; j < 4; ++j) {
      const unsigned char* p = Bt + (wn + j * 16 + l16) * 64 + (quad << 3);
      bfr[j][0] = *(const long*)p;
      bfr[j][1] = *(const long*)(p + 32);
    }
    #pragma unroll
    for (int i = 0; i < 4; ++i)
      #pragma unroll
      for (int j = 0; j < 4; ++j) {
        acc[i][j] = __builtin_amdgcn_mfma_f32_16x16x32_fp8_fp8(
            af[i][0], bfr[j][0], acc[i][j], 0, 0, 0);
        acc[i][j] = __builtin_amdgcn_mfma_f32_16x16x32_fp8_fp8(
            af[i][1], bfr[j][1], acc[i][j], 0, 0, 0);
      }
    __syncthreads();
  }

  const int mbase = blockIdx.y * 128 + wm + quad * 4;
  const int nbase = blockIdx.x * 128 + wn + l16;
  unsigned char* C = E8 + (long)z * SEQ * SEQ;
  float* rs = rowsum + (long)z * SEQ;
  float psum[4][4];
  #pragma unroll
  for (int i = 0; i < 4; ++i)
    #pragma unroll
    for (int r = 0; r < 4; ++r) psum[i][r] = 0.f;

  #pragma unroll
  for (int i = 0; i < 4; ++i) {
    const int row = mbase + i * 16;
    #pragma unroll
    for (int j = 0; j < 4; ++j) {
      const int col = nbase + j * 16;
      #pragma unroll
      for (int r = 0; r < 4; ++r) {
        float e = __expf(acc[i][j][r] * KQ);
        psum[i][r] += e;
        C[(long)(row + r) * SEQ + col] = to_fp8(SE * e);
      }
    }
  }
  #pragma unroll
  for (int i = 0; i < 4; ++i)
    #pragma unroll
    for (int r = 0; r < 4; ++r) {
      float p = psum[i][r];
      p += __shfl_xor(p, 1);
      p += __shfl_xor(p, 2);
      p += __shfl_xor(p, 4);
      p += __shfl_xor(p, 8);
      if (l16 == 0) atomicAdd(&rs[mbase + i * 16 + r], p);
    }
}

// ---------------------------------------------------------------------------
// PV fp8 GEMM 128x128, BK=64: out[c,s] = (sum_t E8[s,t]*V8t[c,t])/(SEV*rowsum)
// + bias2[c], fp32 transposed store into d_out (b,c,s).
// ---------------------------------------------------------------------------
__global__ __launch_bounds__(256) void gemm_pv_norm_f8(
    const unsigned char* __restrict__ E8, const unsigned char* __restrict__ V8t,
    const float* __restrict__ rowsum, const float* __restrict__ bias2,
    float* __restrict__ out) {
  __shared__ unsigned char At[128 * 64];
  __shared__ unsigned char Bt[128 * 64];
  const int tid = threadIdx.x;
  const int z = blockIdx.z;
  const long lK = SEQ;
  const unsigned char* Ab = E8 + (long)z * SEQ * SEQ + (long)blockIdx.y * 128 * lK;
  const unsigned char* Bb = V8t + (long)z * SEQ * CH + (long)blockIdx.x * 128 * lK;

  const int w = tid >> 6, lane = tid & 63;
  const int wm = (w & 1) << 6, wn = (w >> 1) << 6;
  const int l16 = lane & 15, quad = lane >> 4;

  floatx4 acc[4][4];
  #pragma unroll
  for (int i = 0; i < 4; ++i)
    #pragma unroll
    for (int j = 0; j < 4; ++j) acc[i][j] = (floatx4)(0.0f);

  const int row0 = tid >> 2;
  const int part = (tid & 3) << 4;
  for (int kt = 0; kt < SEQ / 64; ++kt) {
    const unsigned char* Ak = Ab + (kt << 6);
    const unsigned char* Bk = Bb + (kt << 6);
    gload16(Ak + (long)row0 * lK + part,        (char*)At + tid * 16);
    gload16(Ak + (long)(row0 + 64) * lK + part, (char*)At + (tid + 256) * 16);
    gload16(Bk + (long)row0 * lK + part,        (char*)Bt + tid * 16);
    gload16(Bk + (long)(row0 + 64) * lK + part, (char*)Bt + (tid + 256) * 16);
    __syncthreads();
    long af[4][2], bfr[4][2];
    #pragma unroll
    for (int i = 0; i < 4; ++i) {
      const unsigned char* p = At + (wm + i * 16 + l16) * 64 + (quad << 3);
      af[i][0] = *(const long*)p;
      af[i][1] = *(const long*)(p + 32);
    }
    #pragma unroll
    for (int j = 0; j < 4; ++j) {
      const unsigned char* p = Bt + (wn + j * 16 + l16) * 64 + (quad << 3);
      bfr[j][0] = *(const long*)p;
      bfr[j][1] = *(const long*)(p + 32);
    }
    #pragma unroll
    for (int i = 0; i < 4; ++i)
      #pragma unroll
      for (int j = 0; j < 4; ++j) {
        acc[i][j] = __builtin_amdgcn_mfma_f32_16x16x32_fp8_fp8(
            af[i][0], bfr[j][0], acc[i][j], 0, 0, 0);
        acc[i][j] = __builtin_amdgcn_mfma_f32_16x16x32_fp8_fp8(
            af[i][1], bfr[j][1], acc[i][j], 0, 0, 0);
      }
    __syncthreads();
  }

  const int mbase = blockIdx.y * 128 + wm + quad * 4;   // s rows, %4 == 0
  const int nbase = blockIdx.x * 128 + wn + l16;        // c cols
  const float* rs = rowsum + (long)z * SEQ;
  float* C = out + (long)z * CH * SEQ;
  floatx4 inv[4];
  #pragma unroll
  for (int i = 0; i < 4; ++i) {
    floatx4 lv = *(const floatx4*)&rs[mbase + i * 16];
    #pragma unroll
    for (int r = 0; r < 4; ++r) inv[i][r] = 1.0f / (SEV * lv[r]);
  }
  #pragma unroll
  for (int j = 0; j < 4; ++j) {
    const int col = nbase + j * 16;
    const float bb = bias2[col];
    #pragma unroll
    for (int i = 0; i < 4; ++i) {
      floatx4 o;
      #pragma unroll
      for (int r = 0; r < 4; ++r) o[r] = acc[i][j][r] * inv[i][r] + bb;
      *(floatx4*)(C + (long)col * SEQ + mbase + i * 16) = o;
    }
  }
}

// ---------------------------------------------------------------------------
extern "C" void kernel_launch(void* const* d_in, const int* in_sizes, int n_in,
                              void* d_out, int out_size, void* d_ws,
                              size_t ws_size, hipStream_t stream) {
  const float* q  = (const float*)d_in[0];
  const float* Wq = (const float*)d_in[1];
  const float* bq = (const float*)d_in[2];
  const float* Wk = (const float*)d_in[3];
  const float* bk = (const float*)d_in[4];
  const float* Wv = (const float*)d_in[5];
  const float* bv = (const float*)d_in[6];
  const float* Wo = (const float*)d_in[7];
  const float* bo = (const float*)d_in[8];
  float* out = (float*)d_out;

  bf16* ws = (bf16*)d_ws;
  const long WSZ = (long)DM * CH;        // 262144
  const long XSZ = (long)SEQ * CH;       // 2097152 (per batch, elements)
  const long SSZ = (long)SEQ * SEQ;      // 16777216
  bf16* Wqb = ws;
  bf16* Wkb = Wqb + WSZ;
  bf16* Wob = Wqb + 2 * WSZ;
  bf16* WvT = Wqb + 3 * WSZ;
  bf16* Wvo = Wqb + 4 * WSZ;
  bf16* xT  = Wqb + 5 * WSZ;                     // bf16 (b,s,c)
  unsigned char* Q8 = (unsigned char*)(xT + BATCH * XSZ);  // (b,s,d) fp8
  unsigned char* K8 = Q8 + BATCH * XSZ;                    // (b,t,d) fp8
  unsigned char* V8 = K8 + BATCH * XSZ;                    // (b,c,s) fp8
  unsigned char* E8 = V8 + BATCH * XSZ;                    // (b,s,t) fp8
  float* bias2  = (float*)(E8 + BATCH * SSZ);              // 512
  float* rowsum = bias2 + 512;                             // BATCH*SEQ

  // --- weight prep ---
  cvt_weights<<<dim3(WSZ / 256, 3), 256, 0, stream>>>(Wq, Wk, Wo, ws);
  transpose_cvt_w<<<dim3(8, 8), 256, 0, stream>>>(Wv, WvT);
  bias_combine<<<dim3(2), 256, 0, stream>>>(Wo, bv, bo, bias2);
  zero_f32<<<dim3(BATCH * SEQ / 256), 256, 0, stream>>>(rowsum);
  gemm_bt_w<<<dim3(4, 4), 256, 0, stream>>>(Wob, WvT, Wvo, DM, CH);

  // --- activations ---
  transpose_cvt<<<dim3(SEQ / 64, CH / 64, BATCH), 256, 0, stream>>>(q, xT);

  gemm_proj_f8<10><<<dim3(8, 32, BATCH), 256, 0, stream>>>(
      xT, XSZ, Wqb, Q8, XSZ, bq);
  gemm_proj_f8<10><<<dim3(8, 32, BATCH), 256, 0, stream>>>(
      xT, XSZ, Wkb, K8, XSZ, bk);
  gemm_proj_f8<11><<<dim3(8, 32, BATCH), 256, 0, stream>>>(
      xT, XSZ, Wvo, V8, XSZ, nullptr);

  // E8 = fp8(SE * exp(KQ * Q8*K8^T)), rowsum (fp32) accumulated atomically
  gemm_qkt_exp_f8<<<dim3(32, 32, BATCH), 256, 0, stream>>>(Q8, K8, E8, rowsum);

  // out = (E8*V8)/(SEV*rowsum) + bias2, fp32 (b,c,s)
  gemm_pv_norm_f8<<<dim3(4, 32, BATCH), 256, 0, stream>>>(
      E8, V8, rowsum, bias2, out);
}